// Round 20
// baseline (73.747 us; speedup 1.0000x reference)
//
#include <hip/hip_runtime.h>

#define EMBED 256
#define NPOS  2304   // 48*48
#define BATCH 4
#define NH    8
#define DH    32

typedef float f32x4  __attribute__((ext_vector_type(4)));
typedef short bf16x8 __attribute__((ext_vector_type(8)));
typedef short s16x4  __attribute__((ext_vector_type(4)));
typedef unsigned u32x4 __attribute__((ext_vector_type(4)));

static __device__ __forceinline__ short f2b(float f) {
    union { float f; unsigned u; } c; c.f = f;
    unsigned r = (c.u + 0x7FFFu + ((c.u >> 16) & 1u)) >> 16;
    return (short)r;
}

static __device__ __forceinline__ unsigned cvtpk(float lo, float hi) {
    unsigned r;
    asm("v_cvt_pk_bf16_f32 %0, %1, %2" : "=v"(r) : "v"(lo), "v"(hi));
    return r;
}

static __device__ __forceinline__ float fexp2(float x) {
    float r;
    asm("v_exp_f32 %0, %1" : "=v"(r) : "v"(x));
    return r;
}

static __device__ __forceinline__ void plswap32(unsigned& a, unsigned& b) {
    asm("v_permlane32_swap_b32 %0, %1" : "+v"(a), "+v"(b));
}
static __device__ __forceinline__ void plswap16(unsigned& a, unsigned& b) {
    asm("v_permlane16_swap_b32 %0, %1" : "+v"(a), "+v"(b));
}

static __device__ __forceinline__ void gl_lds16(const short* g, short* l) {
    __builtin_amdgcn_global_load_lds(
        (const __attribute__((address_space(1))) unsigned int*)(g),
        (__attribute__((address_space(3))) unsigned int*)(l),
        16, 0, 0);
}

// ---------------- kernel 1: weights->bf16 (vectorized) AND xs = transpose(x)+PE ----------------
__global__ __launch_bounds__(256) void prep_all(
        const float* __restrict__ x,
        const float* __restrict__ wq, const float* __restrict__ wk,
        const float* __restrict__ wv, const float* __restrict__ wo,
        short* __restrict__ wqkv, short* __restrict__ wob,
        short* __restrict__ xs) {
    __shared__ float xt[32][65];
    int blk = blockIdx.x;
    int t = threadIdx.x;
    if (blk < 256) {
        int g4 = (blk * 256 + t) * 4;
        if (g4 < 196608) {
            int j = g4 >> 8, kk = g4 & 255;
            int proj = j >> 8, jj = j & 255;
            const float* s = (proj == 0) ? wq : (proj == 1) ? wk : wv;
            f32x4 w = *(const f32x4*)&s[jj * 256 + kk];
            s16x4 o4;
#pragma unroll
            for (int r = 0; r < 4; ++r) o4[r] = f2b(w[r]);
            *(s16x4*)&wqkv[g4] = o4;
        } else {
            int h2 = g4 - 196608;
            f32x4 w = *(const f32x4*)&wo[h2];
            s16x4 o4;
#pragma unroll
            for (int r = 0; r < 4; ++r) o4[r] = f2b(w[r]);
            *(s16x4*)&wob[h2] = o4;
        }
        return;
    }
    int bx = blk - 256;
    int b = bx / 288, rem = bx % 288;
    int c0 = (rem / 36) * 32, pos0 = (rem % 36) * 64;
    int j = t & 63, i0 = t >> 6;
    const float* xp = x + (size_t)(b * EMBED + c0) * NPOS + pos0;
#pragma unroll
    for (int rr = 0; rr < 8; ++rr) {
        int i = rr * 4 + i0;
        xt[i][j] = xp[(size_t)i * NPOS + j];
    }
    __syncthreads();
    int ii = (t & 15) * 2, jj0 = t >> 4;
    const float kln = -0.07195578415606394f;  // -ln(10000)/128
#pragma unroll
    for (int pp = 0; pp < 4; ++pp) {
        int jj = pp * 16 + jj0;
        int pos = pos0 + jj;
        float v0 = xt[ii][jj], v1 = xt[ii + 1][jj];
        float pe0 = 0.f, pe1 = 0.f;
        if (pos > 0) {
            int c = c0 + ii;
            float a0 = (float)pos * __expf((float)c * kln);
            float a1 = (float)pos * __expf((float)(c + 1) * kln);
            pe0 = __sinf(a0);   // even col -> sin
            pe1 = __cosf(a1);   // odd col -> cos
        }
        unsigned lo = (unsigned short)f2b(v0 + pe0);
        unsigned hi = (unsigned short)f2b(v1 + pe1);
        *reinterpret_cast<unsigned*>(xs + (size_t)(b * NPOS + pos) * EMBED + c0 + ii) =
            lo | (hi << 16);
    }
}

// ---------------- kernel 2: QKV GEMM (64x64 tiles, BK=64) ----------------
// Q/K blocks use SWAPPED operands (A=w from b_sm, B=xs from a_sm) -> contiguous stores.
// vt layout: [bh][tile = pos/32][d (32)][k = pos%32]
__global__ __launch_bounds__(256) void gemm_qkv(
        const short* __restrict__ A, const short* __restrict__ Bw,
        const float* __restrict__ bq, const float* __restrict__ bk,
        const float* __restrict__ bv,
        short* __restrict__ qd, short* __restrict__ kd, short* __restrict__ vtd) {
    __shared__ short a_sm[64 * 64];   // 8KB, 16B-block swizzle: blk ^ (row&7)
    __shared__ short b_sm[64 * 64];   // 8KB
    int bx = blockIdx.x;            // 144 x 12
    int bm = bx / 12, bn = bx % 12;
    int m0 = bm * 64, n0 = bn * 64;
    int proj = bn >> 2;             // 0:Q 1:K 2:V (uniform per block)
    int t = threadIdx.x;
    int lane = t & 63, wid = t >> 6;
    int wm = wid >> 1, wn = wid & 1;
    int l15 = lane & 15, l4 = lane >> 4;

    int srow = t >> 2, sblk = t & 3;
    const short* ag = &A[(size_t)(m0 + srow) * 256 + sblk * 8];
    const short* bg = &Bw[(size_t)(n0 + srow) * 256 + sblk * 8];
    int sw0 = ((sblk ^ (srow & 7)) * 8);
    int sw1 = (((sblk + 4) ^ (srow & 7)) * 8);
    short* al0 = &a_sm[srow * 64 + sw0];
    short* al1 = &a_sm[srow * 64 + sw1];
    short* bl0 = &b_sm[srow * 64 + sw0];
    short* bl1 = &b_sm[srow * 64 + sw1];

    const float qs = 0.2550348623f;  // log2(e)/sqrt(32)
    int b = bm / 36;
    int pos0 = m0 - b * NPOS;

    if (proj < 2) {
        // ---- swapped path: D[w-row][pos] ----
        const float* bias = (proj == 0) ? bq : bk;
        f32x4 acc[2][2];
#pragma unroll
        for (int mi = 0; mi < 2; ++mi) {
            int jj0 = (n0 & 255) + wm * 32 + mi * 16 + l4 * 4;
            f32x4 bi = {bias[jj0], bias[jj0 + 1], bias[jj0 + 2], bias[jj0 + 3]};
            acc[mi][0] = bi;
            acc[mi][1] = bi;
        }
        for (int ks = 0; ks < 4; ++ks) {
            __syncthreads();
            *(bf16x8*)al0 = *(const bf16x8*)(ag + ks * 64);
            *(bf16x8*)al1 = *(const bf16x8*)(ag + ks * 64 + 32);
            *(bf16x8*)bl0 = *(const bf16x8*)(bg + ks * 64);
            *(bf16x8*)bl1 = *(const bf16x8*)(bg + ks * 64 + 32);
            __syncthreads();
#pragma unroll
            for (int kk = 0; kk < 2; ++kk) {
                int blk = kk * 4 + l4;
                bf16x8 af[2], bf[2];
#pragma unroll
                for (int mi = 0; mi < 2; ++mi) {
                    int wr = wm * 32 + mi * 16 + l15;
                    af[mi] = *(const bf16x8*)&b_sm[wr * 64 + ((blk ^ (wr & 7)) * 8)];
                }
#pragma unroll
                for (int ni = 0; ni < 2; ++ni) {
                    int pr = wn * 32 + ni * 16 + l15;
                    bf[ni] = *(const bf16x8*)&a_sm[pr * 64 + ((blk ^ (pr & 7)) * 8)];
                }
#pragma unroll
                for (int mi = 0; mi < 2; ++mi)
#pragma unroll
                    for (int ni = 0; ni < 2; ++ni)
                        acc[mi][ni] = __builtin_amdgcn_mfma_f32_16x16x32_bf16(
                            af[mi], bf[ni], acc[mi][ni], 0, 0, 0);
            }
        }
        short* dst = (proj == 0) ? qd : kd;
        float sc = (proj == 0) ? qs : 1.0f;
#pragma unroll
        for (int mi = 0; mi < 2; ++mi) {
            int jj0 = (n0 & 255) + wm * 32 + mi * 16 + l4 * 4;
            int h = jj0 >> 5, d0 = jj0 & 31;
#pragma unroll
            for (int ni = 0; ni < 2; ++ni) {
                int pos = pos0 + wn * 32 + ni * 16 + l15;
                s16x4 pk;
#pragma unroll
                for (int r = 0; r < 4; ++r) pk[r] = f2b(acc[mi][ni][r] * sc);
                *(s16x4*)&dst[((size_t)(b * NH + h) * NPOS + pos) * DH + d0] = pk;
            }
        }
    } else {
        // ---- unswapped path: D[pos][w-col] (V -> tiled vt) ----
        f32x4 acc[2][2];
#pragma unroll
        for (int ni = 0; ni < 2; ++ni) {
            int jj = (n0 & 255) + wn * 32 + ni * 16 + l15;
            float bias = bv[jj];
            f32x4 bi = {bias, bias, bias, bias};
            acc[0][ni] = bi;
            acc[1][ni] = bi;
        }
        for (int ks = 0; ks < 4; ++ks) {
            __syncthreads();
            *(bf16x8*)al0 = *(const bf16x8*)(ag + ks * 64);
            *(bf16x8*)al1 = *(const bf16x8*)(ag + ks * 64 + 32);
            *(bf16x8*)bl0 = *(const bf16x8*)(bg + ks * 64);
            *(bf16x8*)bl1 = *(const bf16x8*)(bg + ks * 64 + 32);
            __syncthreads();
#pragma unroll
            for (int kk = 0; kk < 2; ++kk) {
                int blk = kk * 4 + l4;
                bf16x8 af[2], bf[2];
#pragma unroll
                for (int mi = 0; mi < 2; ++mi) {
                    int ar = wm * 32 + mi * 16 + l15;
                    af[mi] = *(const bf16x8*)&a_sm[ar * 64 + ((blk ^ (ar & 7)) * 8)];
                }
#pragma unroll
                for (int ni = 0; ni < 2; ++ni) {
                    int br = wn * 32 + ni * 16 + l15;
                    bf[ni] = *(const bf16x8*)&b_sm[br * 64 + ((blk ^ (br & 7)) * 8)];
                }
#pragma unroll
                for (int mi = 0; mi < 2; ++mi)
#pragma unroll
                    for (int ni = 0; ni < 2; ++ni)
                        acc[mi][ni] = __builtin_amdgcn_mfma_f32_16x16x32_bf16(
                            af[mi], bf[ni], acc[mi][ni], 0, 0, 0);
            }
        }
#pragma unroll
        for (int mi = 0; mi < 2; ++mi) {
            int pos = pos0 + wm * 32 + mi * 16 + l4 * 4;
#pragma unroll
            for (int ni = 0; ni < 2; ++ni) {
                int jj = (n0 & 255) + wn * 32 + ni * 16 + l15;
                int h = jj >> 5, d = jj & 31;
                s16x4 pk;
#pragma unroll
                for (int r = 0; r < 4; ++r) pk[r] = f2b(acc[mi][ni][r]);
                *(s16x4*)&vtd[(((size_t)(b * NH + h) * 72 + (pos >> 5)) << 10)
                              + d * 32 + (pos & 31)] = pk;
            }
        }
    }
}

// ---------------- kernel 3: flash attention (2-stage cross-tile software pipeline) ----------------
// Per iteration: QK^T of tile t (matrix pipe) overlaps softmax+PV of tile t-1
// (trans+VALU pipes) within the same wave. Staging/vmcnt schedule identical to R19.

__global__ __launch_bounds__(256) void attn_fwd(
        const short* __restrict__ Q, const short* __restrict__ K,
        const short* __restrict__ VT, short* __restrict__ AO) {
    __shared__ short smem[16384];   // 32KB = 4 regions x 4096 shorts (K dbuf 2KB | V dbuf 2KB)

    int bx0 = blockIdx.x;
    int bx = (bx0 & 7) * 144 + (bx0 >> 3);   // 1152 = 8*144: bijective, same-bh -> same XCD
    int bh = bx / 36, qg = bx % 36;
    int q0 = qg * 64;
    int t = threadIdx.x, lane = t & 63, wid = t >> 6;
    int l15 = lane & 15, l4 = lane >> 4;

    const short* Qb = Q + ((size_t)bh * NPOS + q0) * DH;
    bf16x8 qf[4];
#pragma unroll
    for (int qt = 0; qt < 4; ++qt)
        qf[qt] = *(const bf16x8*)&Qb[(qt * 16 + l15) * DH + l4 * 8];

    int ra = lane >> 2, blk = lane & 3;
    int swzk = (ra >> 1) & 3;
    int swzv = (ra & 3) ^ ((ra >> 2) & 3);
    int kv0 = wid * 576;
    const short* kga = K + ((size_t)bh * NPOS + kv0 + ra) * DH + ((blk ^ swzk) * 8);
    const short* vga = VT + (((size_t)bh * 72 + wid * 18) << 10)
                          + ra * 32 + ((blk ^ swzv) * 8);

    short* kbuf = smem + wid * 4096;
    short* vbuf = kbuf + 2048;

    // issue tiles 0,1
#pragma unroll
    for (int p = 0; p < 2; ++p) {
        gl_lds16(kga + p * 1024,            kbuf + p * 1024);
        gl_lds16(kga + p * 1024 + 16 * DH,  kbuf + p * 1024 + 512);
        gl_lds16(vga + p * 1024,            vbuf + p * 1024);
        gl_lds16(vga + p * 1024 + 512,      vbuf + p * 1024 + 512);
    }

    f32x4 zero = {0.f, 0.f, 0.f, 0.f};
    f32x4 o[2][4];
    f32x4 lacc[4];
#pragma unroll
    for (int qt = 0; qt < 4; ++qt) { o[0][qt] = zero; o[1][qt] = zero; lacc[qt] = zero; }
    const float MB = -17.312340490667561f;  // -12*log2(e)
    const f32x4 mb = {MB, MB, MB, MB};
    const u32x4 ones_u = {0x3F803F80u, 0x3F803F80u, 0x3F803F80u, 0x3F803F80u};
    const bf16x8 ones = __builtin_bit_cast(bf16x8, ones_u);

    int kswr = (l4 ^ ((l15 >> 1) & 3)) * 8;
    int vswr = (l4 ^ ((l15 & 3) ^ ((l15 >> 2) & 3))) * 8;

    // pipeline state: s of tile t-1 and its V fragments
    f32x4 sP[4][2];
    bf16x8 vfP0, vfP1;

    // ---- prologue: QK of tile 0 ----
    {
        asm volatile("s_waitcnt vmcnt(4)" ::: "memory");
        bf16x8 kf0 = *(const bf16x8*)&kbuf[l15 * 32 + kswr];
        bf16x8 kf1 = *(const bf16x8*)&kbuf[(16 + l15) * 32 + kswr];
        vfP0 = *(const bf16x8*)&vbuf[l15 * 32 + vswr];
        vfP1 = *(const bf16x8*)&vbuf[(16 + l15) * 32 + vswr];
        asm volatile("s_waitcnt lgkmcnt(0)" ::: "memory");
        __builtin_amdgcn_sched_barrier(0);
        // refill tile 2 into buf 0
        gl_lds16(kga + 2 * 1024,            kbuf);
        gl_lds16(kga + 2 * 1024 + 16 * DH,  kbuf + 512);
        gl_lds16(vga + 2 * 1024,            vbuf);
        gl_lds16(vga + 2 * 1024 + 512,      vbuf + 512);
#pragma unroll
        for (int qt = 0; qt < 4; ++qt) {
            sP[qt][0] = __builtin_amdgcn_mfma_f32_16x16x32_bf16(kf0, qf[qt], mb, 0, 0, 0);
            sP[qt][1] = __builtin_amdgcn_mfma_f32_16x16x32_bf16(kf1, qf[qt], mb, 0, 0, 0);
        }
    }

    // ---- main loop: QK(tt) || SM+PV(tt-1) ----
#pragma unroll 1
    for (int tt = 1; tt < 18; ++tt) {
        int buf = tt & 1;
        if (tt < 17) asm volatile("s_waitcnt vmcnt(4)" ::: "memory");
        else         asm volatile("s_waitcnt vmcnt(0)" ::: "memory");

        const short* kb = kbuf + buf * 1024;
        const short* vb = vbuf + buf * 1024;
        bf16x8 kf0 = *(const bf16x8*)&kb[l15 * 32 + kswr];
        bf16x8 kf1 = *(const bf16x8*)&kb[(16 + l15) * 32 + kswr];
        bf16x8 vN0 = *(const bf16x8*)&vb[l15 * 32 + vswr];
        bf16x8 vN1 = *(const bf16x8*)&vb[(16 + l15) * 32 + vswr];
        asm volatile("s_waitcnt lgkmcnt(0)" ::: "memory");
        __builtin_amdgcn_sched_barrier(0);

        if (tt + 2 < 18) {
            gl_lds16(kga + (tt + 2) * 1024,            kbuf + buf * 1024);
            gl_lds16(kga + (tt + 2) * 1024 + 16 * DH,  kbuf + buf * 1024 + 512);
            gl_lds16(vga + (tt + 2) * 1024,            vbuf + buf * 1024);
            gl_lds16(vga + (tt + 2) * 1024 + 512,      vbuf + buf * 1024 + 512);
        }

        __builtin_amdgcn_s_setprio(1);
        f32x4 sN[4][2];
#pragma unroll
        for (int qt = 0; qt < 4; ++qt) {
            sN[qt][0] = __builtin_amdgcn_mfma_f32_16x16x32_bf16(kf0, qf[qt], mb, 0, 0, 0);
            sN[qt][1] = __builtin_amdgcn_mfma_f32_16x16x32_bf16(kf1, qf[qt], mb, 0, 0, 0);
        }
#pragma unroll
        for (int qt = 0; qt < 4; ++qt) {
            float e00 = fexp2(sP[qt][0][0]), e01 = fexp2(sP[qt][0][1]);
            float e02 = fexp2(sP[qt][0][2]), e03 = fexp2(sP[qt][0][3]);
            float e10 = fexp2(sP[qt][1][0]), e11 = fexp2(sP[qt][1][1]);
            float e12 = fexp2(sP[qt][1][2]), e13 = fexp2(sP[qt][1][3]);

            unsigned p00 = cvtpk(e00, e01), p01 = cvtpk(e02, e03);
            unsigned p10 = cvtpk(e10, e11), p11 = cvtpk(e12, e13);
            unsigned a0 = p00, b0 = p10;
            plswap32(a0, b0); plswap16(a0, b0);
            unsigned a1 = p01, b1 = p11;
            plswap32(a1, b1); plswap16(a1, b1);
            u32x4 fr = {a0, a1, b0, b1};
            bf16x8 pf = __builtin_bit_cast(bf16x8, fr);

            o[0][qt] = __builtin_amdgcn_mfma_f32_16x16x32_bf16(vfP0, pf, o[0][qt], 0, 0, 0);
            o[1][qt] = __builtin_amdgcn_mfma_f32_16x16x32_bf16(vfP1, pf, o[1][qt], 0, 0, 0);
            lacc[qt] = __builtin_amdgcn_mfma_f32_16x16x32_bf16(ones, pf, lacc[qt], 0, 0, 0);
        }
        __builtin_amdgcn_s_setprio(0);
        // rotate pipeline state
#pragma unroll
        for (int qt = 0; qt < 4; ++qt) { sP[qt][0] = sN[qt][0]; sP[qt][1] = sN[qt][1]; }
        vfP0 = vN0;
        vfP1 = vN1;
    }

    // ---- epilogue: SM+PV of tile 17 ----
    {
        __builtin_amdgcn_s_setprio(1);
#pragma unroll
        for (int qt = 0; qt < 4; ++qt) {
            float e00 = fexp2(sP[qt][0][0]), e01 = fexp2(sP[qt][0][1]);
            float e02 = fexp2(sP[qt][0][2]), e03 = fexp2(sP[qt][0][3]);
            float e10 = fexp2(sP[qt][1][0]), e11 = fexp2(sP[qt][1][1]);
            float e12 = fexp2(sP[qt][1][2]), e13 = fexp2(sP[qt][1][3]);

            unsigned p00 = cvtpk(e00, e01), p01 = cvtpk(e02, e03);
            unsigned p10 = cvtpk(e10, e11), p11 = cvtpk(e12, e13);
            unsigned a0 = p00, b0 = p10;
            plswap32(a0, b0); plswap16(a0, b0);
            unsigned a1 = p01, b1 = p11;
            plswap32(a1, b1); plswap16(a1, b1);
            u32x4 fr = {a0, a1, b0, b1};
            bf16x8 pf = __builtin_bit_cast(bf16x8, fr);

            o[0][qt] = __builtin_amdgcn_mfma_f32_16x16x32_bf16(vfP0, pf, o[0][qt], 0, 0, 0);
            o[1][qt] = __builtin_amdgcn_mfma_f32_16x16x32_bf16(vfP1, pf, o[1][qt], 0, 0, 0);
            lacc[qt] = __builtin_amdgcn_mfma_f32_16x16x32_bf16(ones, pf, lacc[qt], 0, 0, 0);
        }
        __builtin_amdgcn_s_setprio(0);
    }

    // lacc[qt][0] holds the full l for qrow

    __syncthreads();   // staging regions become parking space
    if (wid > 0) {
        f32x4* od = (f32x4*)(smem + wid * 4096);
#pragma unroll
        for (int qt = 0; qt < 4; ++qt) {
#pragma unroll
            for (int dt = 0; dt < 2; ++dt)
                od[(qt * 2 + dt) * 64 + lane] = o[dt][qt];
        }
        if (l4 == 0) {
            float* ld = (float*)smem;
#pragma unroll
            for (int qt = 0; qt < 4; ++qt)
                ld[(wid - 1) * 64 + qt * 16 + l15] = lacc[qt][0];
        }
    }
    __syncthreads();
    if (wid == 0) {
        int b = bh >> 3, h = bh & 7;
        const float* ld = (const float*)smem;
#pragma unroll
        for (int qt = 0; qt < 4; ++qt) {
            float lt = lacc[qt][0] + ld[qt * 16 + l15] + ld[64 + qt * 16 + l15]
                     + ld[128 + qt * 16 + l15];
            float inv = __builtin_amdgcn_rcpf(lt);
            int qrow = q0 + qt * 16 + l15;
            size_t obase = ((size_t)b * NPOS + qrow) * EMBED + h * DH;
#pragma unroll
            for (int dt = 0; dt < 2; ++dt) {
                f32x4 ot = o[dt][qt];
#pragma unroll
                for (int w = 1; w < 4; ++w)
                    ot += ((const f32x4*)(smem + w * 4096))[(qt * 2 + dt) * 64 + lane];
                unsigned x0 = cvtpk(ot[0] * inv, ot[1] * inv);
                unsigned x1 = cvtpk(ot[2] * inv, ot[3] * inv);
                *(unsigned long long*)&AO[obase + dt * 16 + l4 * 4] =
                    (unsigned long long)x0 | ((unsigned long long)x1 << 32);
            }
        }
    }
}

// ---------------- kernel 4: out projection + transpose (32x64 tiles, BK=64) ----------------
__global__ __launch_bounds__(256) void gemm_out(
        const short* __restrict__ A, const short* __restrict__ Bw,
        const float* __restrict__ bo, float* __restrict__ out) {
    __shared__ short a_sm[32 * 64];   // 4KB, blk ^ (row&7) swizzle
    __shared__ short b_sm[64 * 64];   // 8KB
    int bx = blockIdx.x;             // 288 x 4
    int bm = bx >> 2, bn = bx & 3;
    int m0 = bm * 32, n0 = bn * 64;
    int t = threadIdx.x;
    int lane = t & 63, wid = t >> 6;
    int wm = wid >> 1, wn = wid & 1;
    int l15 = lane & 15, l4 = lane >> 4;

    f32x4 acc[2];
#pragma unroll
    for (int ni = 0; ni < 2; ++ni) {
        float bias = bo[n0 + wn * 32 + ni * 16 + l15];
        f32x4 bi = {bias, bias, bias, bias};
        acc[ni] = bi;
    }

    int srow = t >> 2, sblk = t & 3;
    const short* ag = &A[(size_t)(m0 + srow) * 256 + sblk * 8];
    const short* bg = &Bw[(size_t)(n0 + srow) * 256 + sblk * 8];
    int sw0 = ((sblk ^ (srow & 7)) * 8);
    int sw1 = (((sblk + 4) ^ (srow & 7)) * 8);
    short* al0 = &a_sm[srow * 64 + sw0];
    short* al1 = &a_sm[srow * 64 + sw1];
    short* bl0 = &b_sm[srow * 64 + sw0];
    short* bl1 = &b_sm[srow * 64 + sw1];

    for (int ks = 0; ks < 4; ++ks) {
        __syncthreads();
        if (t < 128) {
            *(bf16x8*)al0 = *(const bf16x8*)(ag + ks * 64);
            *(bf16x8*)al1 = *(const bf16x8*)(ag + ks * 64 + 32);
        }
        *(bf16x8*)bl0 = *(const bf16x8*)(bg + ks * 64);
        *(bf16x8*)bl1 = *(const bf16x8*)(bg + ks * 64 + 32);
        __syncthreads();
#pragma unroll
        for (int kk = 0; kk < 2; ++kk) {
            int blk = kk * 4 + l4;
            int ar = wm * 16 + l15;
            bf16x8 af = *(const bf16x8*)&a_sm[ar * 64 + ((blk ^ (ar & 7)) * 8)];
            bf16x8 bf[2];
#pragma unroll
            for (int ni = 0; ni < 2; ++ni) {
                int br = wn * 32 + ni * 16 + l15;
                bf[ni] = *(const bf16x8*)&b_sm[br * 64 + ((blk ^ (br & 7)) * 8)];
            }
#pragma unroll
            for (int ni = 0; ni < 2; ++ni)
                acc[ni] = __builtin_amdgcn_mfma_f32_16x16x32_bf16(af, bf[ni], acc[ni], 0, 0, 0);
        }
    }

    int rowb = m0 + wm * 16 + l4 * 4;
    int b = rowb / NPOS;
    int pos = rowb - b * NPOS;
#pragma unroll
    for (int ni = 0; ni < 2; ++ni) {
        int jcol = n0 + wn * 32 + ni * 16 + l15;
        *(f32x4*)&out[((size_t)(b * EMBED) + jcol) * NPOS + pos] = acc[ni];
    }
}

extern "C" void kernel_launch(void* const* d_in, const int* in_sizes, int n_in,
                              void* d_out, int out_size, void* d_ws, size_t ws_size,
                              hipStream_t stream) {
    const float* x  = (const float*)d_in[0];
    const float* wq = (const float*)d_in[1];
    const float* bq = (const float*)d_in[2];
    const float* wk = (const float*)d_in[3];
    const float* bk = (const float*)d_in[4];
    const float* wv = (const float*)d_in[5];
    const float* bv = (const float*)d_in[6];
    const float* wo = (const float*)d_in[7];
    const float* bo = (const float*)d_in[8];

    char* ws = (char*)d_ws;
    short* wqkv = (short*)(ws);               // 768*256*2   = 393216
    short* wob  = (short*)(ws + 393216);      // 256*256*2   = 131072
    short* xs   = (short*)(ws + 524288);      // 9216*256*2  = 4718592
    short* qb   = (short*)(ws + 5242880);     // 4718592
    short* kb   = (short*)(ws + 9961472);     // 4718592
    short* vtb  = (short*)(ws + 14680064);    // 4718592 (32 bh x 72 tiles x 1024 shorts)
    short* ao   = (short*)(ws + 19398656);    // 4718592 -> total 24117248
    float* out  = (float*)d_out;

    hipLaunchKernelGGL(prep_all, dim3(1408), dim3(256), 0, stream,
                       x, wq, wk, wv, wo, wqkv, wob, xs);
    hipLaunchKernelGGL(gemm_qkv, dim3(1728), dim3(256), 0, stream,
                       xs, wqkv, bq, bk, bv, qb, kb, vtb);
    hipLaunchKernelGGL(attn_fwd, dim3(1152), dim3(256), 0, stream, qb, kb, vtb, ao);
    hipLaunchKernelGGL(gemm_out, dim3(1152), dim3(256), 0, stream, ao, wob, bo, out);
}

// Round 21
// 67.636 us; speedup vs baseline: 1.0904x; 1.0904x over previous
//
#include <hip/hip_runtime.h>

#define EMBED 256
#define NPOS  2304   // 48*48
#define BATCH 4
#define NH    8
#define DH    32

typedef float f32x4  __attribute__((ext_vector_type(4)));
typedef short bf16x8 __attribute__((ext_vector_type(8)));
typedef short s16x4  __attribute__((ext_vector_type(4)));
typedef unsigned u32x4 __attribute__((ext_vector_type(4)));

static __device__ __forceinline__ short f2b(float f) {
    union { float f; unsigned u; } c; c.f = f;
    unsigned r = (c.u + 0x7FFFu + ((c.u >> 16) & 1u)) >> 16;
    return (short)r;
}

static __device__ __forceinline__ unsigned cvtpk(float lo, float hi) {
    unsigned r;
    asm("v_cvt_pk_bf16_f32 %0, %1, %2" : "=v"(r) : "v"(lo), "v"(hi));
    return r;
}

static __device__ __forceinline__ float fexp2(float x) {
    float r;
    asm("v_exp_f32 %0, %1" : "=v"(r) : "v"(x));
    return r;
}

static __device__ __forceinline__ void plswap32(unsigned& a, unsigned& b) {
    asm("v_permlane32_swap_b32 %0, %1" : "+v"(a), "+v"(b));
}
static __device__ __forceinline__ void plswap16(unsigned& a, unsigned& b) {
    asm("v_permlane16_swap_b32 %0, %1" : "+v"(a), "+v"(b));
}

static __device__ __forceinline__ void gl_lds16(const short* g, short* l) {
    __builtin_amdgcn_global_load_lds(
        (const __attribute__((address_space(1))) unsigned int*)(g),
        (__attribute__((address_space(3))) unsigned int*)(l),
        16, 0, 0);
}

// ---------------- kernel 1: weights->bf16 (vectorized) AND xs = transpose(x)+PE ----------------
__global__ __launch_bounds__(256) void prep_all(
        const float* __restrict__ x,
        const float* __restrict__ wq, const float* __restrict__ wk,
        const float* __restrict__ wv, const float* __restrict__ wo,
        short* __restrict__ wqkv, short* __restrict__ wob,
        short* __restrict__ xs) {
    __shared__ float xt[32][65];
    int blk = blockIdx.x;
    int t = threadIdx.x;
    if (blk < 256) {
        int g4 = (blk * 256 + t) * 4;
        if (g4 < 196608) {
            int j = g4 >> 8, kk = g4 & 255;
            int proj = j >> 8, jj = j & 255;
            const float* s = (proj == 0) ? wq : (proj == 1) ? wk : wv;
            f32x4 w = *(const f32x4*)&s[jj * 256 + kk];
            s16x4 o4;
#pragma unroll
            for (int r = 0; r < 4; ++r) o4[r] = f2b(w[r]);
            *(s16x4*)&wqkv[g4] = o4;
        } else {
            int h2 = g4 - 196608;
            f32x4 w = *(const f32x4*)&wo[h2];
            s16x4 o4;
#pragma unroll
            for (int r = 0; r < 4; ++r) o4[r] = f2b(w[r]);
            *(s16x4*)&wob[h2] = o4;
        }
        return;
    }
    int bx = blk - 256;
    int b = bx / 288, rem = bx % 288;
    int c0 = (rem / 36) * 32, pos0 = (rem % 36) * 64;
    int j = t & 63, i0 = t >> 6;
    const float* xp = x + (size_t)(b * EMBED + c0) * NPOS + pos0;
#pragma unroll
    for (int rr = 0; rr < 8; ++rr) {
        int i = rr * 4 + i0;
        xt[i][j] = xp[(size_t)i * NPOS + j];
    }
    __syncthreads();
    int ii = (t & 15) * 2, jj0 = t >> 4;
    const float kln = -0.07195578415606394f;  // -ln(10000)/128
#pragma unroll
    for (int pp = 0; pp < 4; ++pp) {
        int jj = pp * 16 + jj0;
        int pos = pos0 + jj;
        float v0 = xt[ii][jj], v1 = xt[ii + 1][jj];
        float pe0 = 0.f, pe1 = 0.f;
        if (pos > 0) {
            int c = c0 + ii;
            float a0 = (float)pos * __expf((float)c * kln);
            float a1 = (float)pos * __expf((float)(c + 1) * kln);
            pe0 = __sinf(a0);   // even col -> sin
            pe1 = __cosf(a1);   // odd col -> cos
        }
        unsigned lo = (unsigned short)f2b(v0 + pe0);
        unsigned hi = (unsigned short)f2b(v1 + pe1);
        *reinterpret_cast<unsigned*>(xs + (size_t)(b * NPOS + pos) * EMBED + c0 + ii) =
            lo | (hi << 16);
    }
}

// ---------------- kernel 2: QKV GEMM (64x64 tiles, BK=64) ----------------
// Q/K blocks use SWAPPED operands (A=w from b_sm, B=xs from a_sm) -> contiguous stores.
// vt layout: [bh][tile = pos/32][d (32)][k = pos%32]
__global__ __launch_bounds__(256) void gemm_qkv(
        const short* __restrict__ A, const short* __restrict__ Bw,
        const float* __restrict__ bq, const float* __restrict__ bk,
        const float* __restrict__ bv,
        short* __restrict__ qd, short* __restrict__ kd, short* __restrict__ vtd) {
    __shared__ short a_sm[64 * 64];   // 8KB, 16B-block swizzle: blk ^ (row&7)
    __shared__ short b_sm[64 * 64];   // 8KB
    int bx = blockIdx.x;            // 144 x 12
    int bm = bx / 12, bn = bx % 12;
    int m0 = bm * 64, n0 = bn * 64;
    int proj = bn >> 2;             // 0:Q 1:K 2:V (uniform per block)
    int t = threadIdx.x;
    int lane = t & 63, wid = t >> 6;
    int wm = wid >> 1, wn = wid & 1;
    int l15 = lane & 15, l4 = lane >> 4;

    int srow = t >> 2, sblk = t & 3;
    const short* ag = &A[(size_t)(m0 + srow) * 256 + sblk * 8];
    const short* bg = &Bw[(size_t)(n0 + srow) * 256 + sblk * 8];
    int sw0 = ((sblk ^ (srow & 7)) * 8);
    int sw1 = (((sblk + 4) ^ (srow & 7)) * 8);
    short* al0 = &a_sm[srow * 64 + sw0];
    short* al1 = &a_sm[srow * 64 + sw1];
    short* bl0 = &b_sm[srow * 64 + sw0];
    short* bl1 = &b_sm[srow * 64 + sw1];

    const float qs = 0.2550348623f;  // log2(e)/sqrt(32)
    int b = bm / 36;
    int pos0 = m0 - b * NPOS;

    if (proj < 2) {
        // ---- swapped path: D[w-row][pos] ----
        const float* bias = (proj == 0) ? bq : bk;
        f32x4 acc[2][2];
#pragma unroll
        for (int mi = 0; mi < 2; ++mi) {
            int jj0 = (n0 & 255) + wm * 32 + mi * 16 + l4 * 4;
            f32x4 bi = {bias[jj0], bias[jj0 + 1], bias[jj0 + 2], bias[jj0 + 3]};
            acc[mi][0] = bi;
            acc[mi][1] = bi;
        }
        for (int ks = 0; ks < 4; ++ks) {
            __syncthreads();
            *(bf16x8*)al0 = *(const bf16x8*)(ag + ks * 64);
            *(bf16x8*)al1 = *(const bf16x8*)(ag + ks * 64 + 32);
            *(bf16x8*)bl0 = *(const bf16x8*)(bg + ks * 64);
            *(bf16x8*)bl1 = *(const bf16x8*)(bg + ks * 64 + 32);
            __syncthreads();
#pragma unroll
            for (int kk = 0; kk < 2; ++kk) {
                int blk = kk * 4 + l4;
                bf16x8 af[2], bf[2];
#pragma unroll
                for (int mi = 0; mi < 2; ++mi) {
                    int wr = wm * 32 + mi * 16 + l15;
                    af[mi] = *(const bf16x8*)&b_sm[wr * 64 + ((blk ^ (wr & 7)) * 8)];
                }
#pragma unroll
                for (int ni = 0; ni < 2; ++ni) {
                    int pr = wn * 32 + ni * 16 + l15;
                    bf[ni] = *(const bf16x8*)&a_sm[pr * 64 + ((blk ^ (pr & 7)) * 8)];
                }
#pragma unroll
                for (int mi = 0; mi < 2; ++mi)
#pragma unroll
                    for (int ni = 0; ni < 2; ++ni)
                        acc[mi][ni] = __builtin_amdgcn_mfma_f32_16x16x32_bf16(
                            af[mi], bf[ni], acc[mi][ni], 0, 0, 0);
            }
        }
        short* dst = (proj == 0) ? qd : kd;
        float sc = (proj == 0) ? qs : 1.0f;
#pragma unroll
        for (int mi = 0; mi < 2; ++mi) {
            int jj0 = (n0 & 255) + wm * 32 + mi * 16 + l4 * 4;
            int h = jj0 >> 5, d0 = jj0 & 31;
#pragma unroll
            for (int ni = 0; ni < 2; ++ni) {
                int pos = pos0 + wn * 32 + ni * 16 + l15;
                s16x4 pk;
#pragma unroll
                for (int r = 0; r < 4; ++r) pk[r] = f2b(acc[mi][ni][r] * sc);
                *(s16x4*)&dst[((size_t)(b * NH + h) * NPOS + pos) * DH + d0] = pk;
            }
        }
    } else {
        // ---- unswapped path: D[pos][w-col] (V -> tiled vt) ----
        f32x4 acc[2][2];
#pragma unroll
        for (int ni = 0; ni < 2; ++ni) {
            int jj = (n0 & 255) + wn * 32 + ni * 16 + l15;
            float bias = bv[jj];
            f32x4 bi = {bias, bias, bias, bias};
            acc[0][ni] = bi;
            acc[1][ni] = bi;
        }
        for (int ks = 0; ks < 4; ++ks) {
            __syncthreads();
            *(bf16x8*)al0 = *(const bf16x8*)(ag + ks * 64);
            *(bf16x8*)al1 = *(const bf16x8*)(ag + ks * 64 + 32);
            *(bf16x8*)bl0 = *(const bf16x8*)(bg + ks * 64);
            *(bf16x8*)bl1 = *(const bf16x8*)(bg + ks * 64 + 32);
            __syncthreads();
#pragma unroll
            for (int kk = 0; kk < 2; ++kk) {
                int blk = kk * 4 + l4;
                bf16x8 af[2], bf[2];
#pragma unroll
                for (int mi = 0; mi < 2; ++mi) {
                    int ar = wm * 32 + mi * 16 + l15;
                    af[mi] = *(const bf16x8*)&a_sm[ar * 64 + ((blk ^ (ar & 7)) * 8)];
                }
#pragma unroll
                for (int ni = 0; ni < 2; ++ni) {
                    int br = wn * 32 + ni * 16 + l15;
                    bf[ni] = *(const bf16x8*)&b_sm[br * 64 + ((blk ^ (br & 7)) * 8)];
                }
#pragma unroll
                for (int mi = 0; mi < 2; ++mi)
#pragma unroll
                    for (int ni = 0; ni < 2; ++ni)
                        acc[mi][ni] = __builtin_amdgcn_mfma_f32_16x16x32_bf16(
                            af[mi], bf[ni], acc[mi][ni], 0, 0, 0);
            }
        }
#pragma unroll
        for (int mi = 0; mi < 2; ++mi) {
            int pos = pos0 + wm * 32 + mi * 16 + l4 * 4;
#pragma unroll
            for (int ni = 0; ni < 2; ++ni) {
                int jj = (n0 & 255) + wn * 32 + ni * 16 + l15;
                int h = jj >> 5, d = jj & 31;
                s16x4 pk;
#pragma unroll
                for (int r = 0; r < 4; ++r) pk[r] = f2b(acc[mi][ni][r]);
                *(s16x4*)&vtd[(((size_t)(b * NH + h) * 72 + (pos >> 5)) << 10)
                              + d * 32 + (pos & 31)] = pk;
            }
        }
    }
}

// ---------------- kernel 3: flash attention (64 q-rows/block, 4-way KV split) ----------------
// FROZEN at the round-19 form (best measured: ~47.6-48.4 us).

__global__ __launch_bounds__(256) void attn_fwd(
        const short* __restrict__ Q, const short* __restrict__ K,
        const short* __restrict__ VT, short* __restrict__ AO) {
    __shared__ short smem[16384];   // 32KB = 4 regions x 4096 shorts (K dbuf 2KB | V dbuf 2KB)

    int bx0 = blockIdx.x;
    int bx = (bx0 & 7) * 144 + (bx0 >> 3);   // 1152 = 8*144: bijective, same-bh -> same XCD
    int bh = bx / 36, qg = bx % 36;
    int q0 = qg * 64;
    int t = threadIdx.x, lane = t & 63, wid = t >> 6;
    int l15 = lane & 15, l4 = lane >> 4;

    // Q B-frags (all 4 waves identical): col(l15)=qrow, k(l4*8..)=dh
    const short* Qb = Q + ((size_t)bh * NPOS + q0) * DH;
    bf16x8 qf[4];
#pragma unroll
    for (int qt = 0; qt < 4; ++qt)
        qf[qt] = *(const bf16x8*)&Qb[(qt * 16 + l15) * DH + l4 * 8];

    // per-wave staging sources (pre-swizzled global addr; LDS dest linear)
    int kv0 = wid * 576;
    int ra = lane >> 2, blk = lane & 3;
    int swzk = (ra >> 1) & 3;                       // same for rows ra and 16+ra
    int swzv = (ra & 3) ^ ((ra >> 2) & 3);          // same for d=ra and d=16+ra
    const short* kga = K + ((size_t)bh * NPOS + kv0 + ra) * DH + ((blk ^ swzk) * 8);
    const short* vga = VT + (((size_t)bh * 72 + wid * 18) << 10)
                          + ra * 32 + ((blk ^ swzv) * 8);

    short* kbuf = smem + wid * 4096;
    short* vbuf = kbuf + 2048;

    // issue tiles 0,1 (4 DMAs each)
#pragma unroll
    for (int p = 0; p < 2; ++p) {
        gl_lds16(kga + p * 1024,            kbuf + p * 1024);
        gl_lds16(kga + p * 1024 + 16 * DH,  kbuf + p * 1024 + 512);
        gl_lds16(vga + p * 1024,            vbuf + p * 1024);
        gl_lds16(vga + p * 1024 + 512,      vbuf + p * 1024 + 512);
    }

    f32x4 zero = {0.f, 0.f, 0.f, 0.f};
    f32x4 o[2][4];                      // [dt][qt]
    f32x4 lacc[4];
#pragma unroll
    for (int qt = 0; qt < 4; ++qt) { o[0][qt] = zero; o[1][qt] = zero; lacc[qt] = zero; }
    const float MB = -17.312340490667561f;  // -12*log2(e)
    const f32x4 mb = {MB, MB, MB, MB};
    const u32x4 ones_u = {0x3F803F80u, 0x3F803F80u, 0x3F803F80u, 0x3F803F80u};
    const bf16x8 ones = __builtin_bit_cast(bf16x8, ones_u);

    int kswr = (l4 ^ ((l15 >> 1) & 3)) * 8;                       // K read swizzle
    int vswr = (l4 ^ ((l15 & 3) ^ ((l15 >> 2) & 3))) * 8;         // V read swizzle

#pragma unroll 1
    for (int tt = 0; tt < 18; ++tt) {
        int buf = tt & 1;
        if (tt < 17) asm volatile("s_waitcnt vmcnt(4)" ::: "memory");
        else         asm volatile("s_waitcnt vmcnt(0)" ::: "memory");

        const short* kb = kbuf + buf * 1024;
        const short* vb = vbuf + buf * 1024;
        bf16x8 kf0 = *(const bf16x8*)&kb[l15 * 32 + kswr];
        bf16x8 kf1 = *(const bf16x8*)&kb[(16 + l15) * 32 + kswr];
        bf16x8 vf0 = *(const bf16x8*)&vb[l15 * 32 + vswr];
        bf16x8 vf1 = *(const bf16x8*)&vb[(16 + l15) * 32 + vswr];
        asm volatile("s_waitcnt lgkmcnt(0)" ::: "memory");
        __builtin_amdgcn_sched_barrier(0);

        if (tt + 2 < 18) {   // refill this buffer for tile tt+2
            gl_lds16(kga + (tt + 2) * 1024,            kbuf + buf * 1024);
            gl_lds16(kga + (tt + 2) * 1024 + 16 * DH,  kbuf + buf * 1024 + 512);
            gl_lds16(vga + (tt + 2) * 1024,            vbuf + buf * 1024);
            gl_lds16(vga + (tt + 2) * 1024 + 512,      vbuf + buf * 1024 + 512);
        }

        __builtin_amdgcn_s_setprio(1);
#pragma unroll
        for (int qt = 0; qt < 4; ++qt) {
            f32x4 s0 = __builtin_amdgcn_mfma_f32_16x16x32_bf16(kf0, qf[qt], mb, 0, 0, 0);
            f32x4 s1 = __builtin_amdgcn_mfma_f32_16x16x32_bf16(kf1, qf[qt], mb, 0, 0, 0);

            float e00 = fexp2(s0[0]), e01 = fexp2(s0[1]), e02 = fexp2(s0[2]), e03 = fexp2(s0[3]);
            float e10 = fexp2(s1[0]), e11 = fexp2(s1[1]), e12 = fexp2(s1[2]), e13 = fexp2(s1[3]);

            unsigned p00 = cvtpk(e00, e01), p01 = cvtpk(e02, e03);
            unsigned p10 = cvtpk(e10, e11), p11 = cvtpk(e12, e13);
            unsigned a0 = p00, b0 = p10;
            plswap32(a0, b0); plswap16(a0, b0);
            unsigned a1 = p01, b1 = p11;
            plswap32(a1, b1); plswap16(a1, b1);
            u32x4 fr = {a0, a1, b0, b1};
            bf16x8 pf = __builtin_bit_cast(bf16x8, fr);

            o[0][qt] = __builtin_amdgcn_mfma_f32_16x16x32_bf16(vf0, pf, o[0][qt], 0, 0, 0);
            o[1][qt] = __builtin_amdgcn_mfma_f32_16x16x32_bf16(vf1, pf, o[1][qt], 0, 0, 0);
            lacc[qt] = __builtin_amdgcn_mfma_f32_16x16x32_bf16(ones, pf, lacc[qt], 0, 0, 0);
        }
        __builtin_amdgcn_s_setprio(0);
    }

    // lacc[qt][0] already holds the full l for qrow (identical across l4 groups and regs)

    __syncthreads();   // all waves done with staging (wave 0's region becomes l-parking)
    if (wid > 0) {
        f32x4* od = (f32x4*)(smem + wid * 4096);    // own dead region: exactly 8KB of o
#pragma unroll
        for (int qt = 0; qt < 4; ++qt) {
#pragma unroll
            for (int dt = 0; dt < 2; ++dt)
                od[(qt * 2 + dt) * 64 + lane] = o[dt][qt];
        }
        if (l4 == 0) {
            float* ld = (float*)smem;               // wave 0's dead region: deduped l
#pragma unroll
            for (int qt = 0; qt < 4; ++qt)
                ld[(wid - 1) * 64 + qt * 16 + l15] = lacc[qt][0];
        }
    }
    __syncthreads();
    if (wid == 0) {
        int b = bh >> 3, h = bh & 7;
        const float* ld = (const float*)smem;
#pragma unroll
        for (int qt = 0; qt < 4; ++qt) {
            float lt = lacc[qt][0] + ld[qt * 16 + l15] + ld[64 + qt * 16 + l15]
                     + ld[128 + qt * 16 + l15];
            float inv = __builtin_amdgcn_rcpf(lt);
            int qrow = q0 + qt * 16 + l15;
            size_t obase = ((size_t)b * NPOS + qrow) * EMBED + h * DH;
#pragma unroll
            for (int dt = 0; dt < 2; ++dt) {
                f32x4 ot = o[dt][qt];
#pragma unroll
                for (int w = 1; w < 4; ++w)
                    ot += ((const f32x4*)(smem + w * 4096))[(qt * 2 + dt) * 64 + lane];
                unsigned x0 = cvtpk(ot[0] * inv, ot[1] * inv);
                unsigned x1 = cvtpk(ot[2] * inv, ot[3] * inv);
                *(unsigned long long*)&AO[obase + dt * 16 + l4 * 4] =
                    (unsigned long long)x0 | ((unsigned long long)x1 << 32);
            }
        }
    }
}

// ---------------- kernel 4: out projection + transpose (64x64 tiles, BK=64) ----------------
__global__ __launch_bounds__(256) void gemm_out(
        const short* __restrict__ A, const short* __restrict__ Bw,
        const float* __restrict__ bo, float* __restrict__ out) {
    __shared__ short a_sm[64 * 64];   // 8KB, blk ^ (row&7) swizzle
    __shared__ short b_sm[64 * 64];   // 8KB
    int bx = blockIdx.x;             // 144 x 4
    int bm = bx >> 2, bn = bx & 3;
    int m0 = bm * 64, n0 = bn * 64;
    int t = threadIdx.x;
    int lane = t & 63, wid = t >> 6;
    int wm = wid >> 1, wn = wid & 1;
    int l15 = lane & 15, l4 = lane >> 4;

    f32x4 acc[2][2];
#pragma unroll
    for (int ni = 0; ni < 2; ++ni) {
        float bias = bo[n0 + wn * 32 + ni * 16 + l15];
        f32x4 bi = {bias, bias, bias, bias};
        acc[0][ni] = bi;
        acc[1][ni] = bi;
    }

    int srow = t >> 2, sblk = t & 3;
    const short* ag = &A[(size_t)(m0 + srow) * 256 + sblk * 8];
    const short* bg = &Bw[(size_t)(n0 + srow) * 256 + sblk * 8];
    int sw0 = ((sblk ^ (srow & 7)) * 8);
    int sw1 = (((sblk + 4) ^ (srow & 7)) * 8);
    short* al0 = &a_sm[srow * 64 + sw0];
    short* al1 = &a_sm[srow * 64 + sw1];
    short* bl0 = &b_sm[srow * 64 + sw0];
    short* bl1 = &b_sm[srow * 64 + sw1];

    for (int ks = 0; ks < 4; ++ks) {
        __syncthreads();
        *(bf16x8*)al0 = *(const bf16x8*)(ag + ks * 64);
        *(bf16x8*)al1 = *(const bf16x8*)(ag + ks * 64 + 32);
        *(bf16x8*)bl0 = *(const bf16x8*)(bg + ks * 64);
        *(bf16x8*)bl1 = *(const bf16x8*)(bg + ks * 64 + 32);
        __syncthreads();
#pragma unroll
        for (int kk = 0; kk < 2; ++kk) {
            int blk = kk * 4 + l4;
            bf16x8 af[2], bf[2];
#pragma unroll
            for (int mi = 0; mi < 2; ++mi) {
                int ar = wm * 32 + mi * 16 + l15;
                af[mi] = *(const bf16x8*)&a_sm[ar * 64 + ((blk ^ (ar & 7)) * 8)];
            }
#pragma unroll
            for (int ni = 0; ni < 2; ++ni) {
                int br = wn * 32 + ni * 16 + l15;
                bf[ni] = *(const bf16x8*)&b_sm[br * 64 + ((blk ^ (br & 7)) * 8)];
            }
#pragma unroll
            for (int mi = 0; mi < 2; ++mi)
#pragma unroll
                for (int ni = 0; ni < 2; ++ni)
                    acc[mi][ni] = __builtin_amdgcn_mfma_f32_16x16x32_bf16(
                        af[mi], bf[ni], acc[mi][ni], 0, 0, 0);
        }
    }

    int b = bm / 36;
    int pos0 = m0 - b * NPOS;
#pragma unroll
    for (int mi = 0; mi < 2; ++mi) {
        int pos = pos0 + wm * 32 + mi * 16 + l4 * 4;
#pragma unroll
        for (int ni = 0; ni < 2; ++ni) {
            int jcol = n0 + wn * 32 + ni * 16 + l15;
            *(f32x4*)&out[((size_t)(b * EMBED) + jcol) * NPOS + pos] = acc[mi][ni];
        }
    }
}

extern "C" void kernel_launch(void* const* d_in, const int* in_sizes, int n_in,
                              void* d_out, int out_size, void* d_ws, size_t ws_size,
                              hipStream_t stream) {
    const float* x  = (const float*)d_in[0];
    const float* wq = (const float*)d_in[1];
    const float* bq = (const float*)d_in[2];
    const float* wk = (const float*)d_in[3];
    const float* bk = (const float*)d_in[4];
    const float* wv = (const float*)d_in[5];
    const float* bv = (const float*)d_in[6];
    const float* wo = (const float*)d_in[7];
    const float* bo = (const float*)d_in[8];

    char* ws = (char*)d_ws;
    short* wqkv = (short*)(ws);               // 768*256*2   = 393216
    short* wob  = (short*)(ws + 393216);      // 256*256*2   = 131072
    short* xs   = (short*)(ws + 524288);      // 9216*256*2  = 4718592
    short* qb   = (short*)(ws + 5242880);     // 4718592
    short* kb   = (short*)(ws + 9961472);     // 4718592
    short* vtb  = (short*)(ws + 14680064);    // 4718592 (32 bh x 72 tiles x 1024 shorts)
    short* ao   = (short*)(ws + 19398656);    // 4718592 -> total 24117248
    float* out  = (float*)d_out;

    hipLaunchKernelGGL(prep_all, dim3(1408), dim3(256), 0, stream,
                       x, wq, wk, wv, wo, wqkv, wob, xs);
    hipLaunchKernelGGL(gemm_qkv, dim3(1728), dim3(256), 0, stream,
                       xs, wqkv, bq, bk, bv, qb, kb, vtb);
    hipLaunchKernelGGL(attn_fwd, dim3(1152), dim3(256), 0, stream, qb, kb, vtb, ao);
    hipLaunchKernelGGL(gemm_out, dim3(576), dim3(256), 0, stream, ao, wob, bo, out);
}